// Round 8
// baseline (81.376 us; speedup 1.0000x reference)
//
#include <hip/hip_runtime.h>

// DenseWarp: out[b,c,y,x] = bilinear(frame[b,c], qy, qx)
//   qy = clip(y - flow[b,0,y,x], 0, H-1), qx = clip(x - flow[b,1,y,x], 0, W-1)
// fp32 in/out. B=4, C=4, H=1080, W=1920.
//
// R8 = R7 with the BIJECTIVE XCD swizzle (R7 failed because 8100 % 8 != 0,
// the simple swizzle double-mapped blocks -> unwritten pixels). Two-pass:
//   1) NCHW -> NHWC fp16 prepass into d_ws (nontemporal frame reads)
//   2) quad-per-thread gather: 2 float4 flow loads, 8 h8 gathers,
//      4 dwordx4 plane stores = 3.5 VMEM/px (vs 8 in R5).

#define BB 4
#define CC 4
#define HH 1080
#define WW 1920
#define HW (HH * WW)
#define NPX (BB * HH * WW)              // 8,294,400 pixels (b,y,x)
#define WS_BYTES ((size_t)NPX * CC * 2) // 66,355,200 B
#define NBLK_Q (NPX / 4 / 256)          // 8,100 (NOT div by 8 -> bijective swz)
#define NBLK_F (NPX / 256)              // 32,400

typedef _Float16 h8 __attribute__((ext_vector_type(8), aligned(8)));
typedef float f32x4 __attribute__((ext_vector_type(4), aligned(16)));
typedef float f32x2 __attribute__((ext_vector_type(2), aligned(4)));

// m204 bijective XCD swizzle: XCD k gets a contiguous chunk of q (+1 for k<r)
// blocks; valid for ANY nblk.
__device__ __forceinline__ int xcd_swizzle(int n, int nblk)
{
    const int q   = nblk >> 3;
    const int r   = nblk & 7;
    const int xcd = n & 7;
    const int loc = n >> 3;
    const int base = (xcd < r) ? xcd * (q + 1) : r * (q + 1) + (xcd - r) * q;
    return base + loc;
}

__global__ __launch_bounds__(256) void nhwc_fp16_prepass(
    const float* __restrict__ frame,
    _Float16* __restrict__ ws)
{
    const int blk = xcd_swizzle(blockIdx.x, NBLK_Q);
    const int p   = (blk * 256 + threadIdx.x) * 4;   // first of 4 pixels
    const int x = p % WW;
    const int t = p / WW;
    const int y = t % HH;
    const int b = t / HH;

    const size_t off = (size_t)(b * CC) * HW + (size_t)y * WW + x;
    h8 o1, o2;
#pragma unroll
    for (int c = 0; c < CC; ++c) {
        // nontemporal: frame is read exactly once; keep LLC for ws
        const f32x4 v = __builtin_nontemporal_load(
            reinterpret_cast<const f32x4*>(frame + off + (size_t)c * HW));
        o1[c]     = (_Float16)v.x;
        o1[c + 4] = (_Float16)v.y;
        o2[c]     = (_Float16)v.z;
        o2[c + 4] = (_Float16)v.w;
    }
    // regular stores: ws should be LLC-resident for the gather pass
    *reinterpret_cast<h8*>(ws + (size_t)p * 4)     = o1;
    *reinterpret_cast<h8*>(ws + (size_t)p * 4 + 8) = o2;
}

__global__ __launch_bounds__(256) void dense_warp_gather(
    const _Float16* __restrict__ ws,
    const float* __restrict__ flow,
    float* __restrict__ out)
{
    const int blk = xcd_swizzle(blockIdx.x, NBLK_Q);
    const int p   = (blk * 256 + threadIdx.x) * 4;   // first of 4 pixels
    const int x = p % WW;
    const int t = p / WW;
    const int y = t % HH;
    const int b = t / HH;

    const size_t rowoff = (size_t)y * WW + x;
    const float* __restrict__ flowy = flow + (size_t)(b * 2) * HW;
    const float* __restrict__ flowx = flowy + HW;
    const _Float16* __restrict__ wsb = ws + (size_t)b * HW * 4;
    float* __restrict__ outb = out + (size_t)(b * CC) * HW;

    const f32x4 fy4 = *reinterpret_cast<const f32x4*>(flowy + rowoff);
    const f32x4 fx4 = *reinterpret_cast<const f32x4*>(flowx + rowoff);

    f32x4 res[CC];

#pragma unroll
    for (int i = 0; i < 4; ++i) {
        const float fy = fy4[i];
        const float fx = fx4[i];

        // same op order as reference
        const float qy  = fminf(fmaxf((float)y - fy, 0.0f), (float)(HH - 1));
        const float qx  = fminf(fmaxf((float)(x + i) - fx, 0.0f), (float)(WW - 1));
        const float y0f = floorf(qy);
        const float x0f = floorf(qx);
        const float wy  = qy - y0f;
        float       wx  = qx - x0f;
        const int y0 = (int)y0f;
        const int x0 = (int)x0f;
        const int y1 = min(y0 + 1, HH - 1);

        // right-edge: x0==W-1 -> wx==0; load pair at W-2 with wx=1 (identical)
        const bool edge = (x0 > WW - 2);
        const int  xb   = edge ? (WW - 2) : x0;
        if (edge) wx = 1.0f;

        // one 16B load per row covers 4 channels x 2 pixels (NHWC fp16)
        const h8 tp = *reinterpret_cast<const h8*>(wsb + ((size_t)y0 * WW + xb) * 4);
        const h8 bt = *reinterpret_cast<const h8*>(wsb + ((size_t)y1 * WW + xb) * 4);

        const float omwx = 1.0f - wx;
        const float omwy = 1.0f - wy;

#pragma unroll
        for (int c = 0; c < CC; ++c) {
            const float tl = (float)tp[c];
            const float tr = (float)tp[c + 4];
            const float bl = (float)bt[c];
            const float br = (float)bt[c + 4];
            const float top = tl * omwx + tr * wx;
            const float bot = bl * omwx + br * wx;
            res[c][i] = top * omwy + bot * wy;
        }
    }

    // one dwordx4 store per channel plane
#pragma unroll
    for (int c = 0; c < CC; ++c) {
        __builtin_nontemporal_store(
            res[c], reinterpret_cast<f32x4*>(outb + (size_t)c * HW + rowoff));
    }
}

// exact-fp32 single-pass fallback if ws_size is insufficient (R3 kernel)
__global__ __launch_bounds__(256) void dense_warp_fallback(
    const float* __restrict__ frame,
    const float* __restrict__ flow,
    float* __restrict__ out)
{
    const int blk = xcd_swizzle(blockIdx.x, NBLK_F);
    const int p   = blk * 256 + threadIdx.x;
    const int x = p % WW;
    const int t = p / WW;
    const int y = t % HH;
    const int b = t / HH;

    const size_t rowoff = (size_t)y * WW + x;
    const float fy = flow[(size_t)(b * 2 + 0) * HW + rowoff];
    const float fx = flow[(size_t)(b * 2 + 1) * HW + rowoff];

    const float qy  = fminf(fmaxf((float)y - fy, 0.0f), (float)(HH - 1));
    const float qx  = fminf(fmaxf((float)x - fx, 0.0f), (float)(WW - 1));
    const float y0f = floorf(qy);
    const float x0f = floorf(qx);
    const float wy  = qy - y0f;
    float       wx  = qx - x0f;
    const int y0 = (int)y0f;
    const int x0 = (int)x0f;
    const int y1 = min(y0 + 1, HH - 1);
    const bool edge = (x0 > WW - 2);
    const int  xb   = edge ? (WW - 2) : x0;
    if (edge) wx = 1.0f;

    const int i0 = y0 * WW + xb;
    const int i1 = y1 * WW + xb;
    const float omwx = 1.0f - wx;
    const float omwy = 1.0f - wy;

#pragma unroll
    for (int c = 0; c < CC; ++c) {
        const float* fp = frame + (size_t)(b * CC + c) * HW;
        const f32x2 t2 = *reinterpret_cast<const f32x2*>(fp + i0);
        const f32x2 b2 = *reinterpret_cast<const f32x2*>(fp + i1);
        const float top = t2.x * omwx + t2.y * wx;
        const float bot = b2.x * omwx + b2.y * wx;
        const float v   = top * omwy + bot * wy;
        __builtin_nontemporal_store(v, out + (size_t)(b * CC + c) * HW + rowoff);
    }
}

extern "C" void kernel_launch(void* const* d_in, const int* in_sizes, int n_in,
                              void* d_out, int out_size, void* d_ws, size_t ws_size,
                              hipStream_t stream)
{
    const float* frame = (const float*)d_in[0];
    const float* flow  = (const float*)d_in[1];
    float* out = (float*)d_out;

    if (ws_size >= WS_BYTES && d_ws != nullptr) {
        _Float16* ws = (_Float16*)d_ws;
        nhwc_fp16_prepass<<<NBLK_Q, 256, 0, stream>>>(frame, ws);
        dense_warp_gather<<<NBLK_Q, 256, 0, stream>>>(ws, flow, out);
    } else {
        dense_warp_fallback<<<NBLK_F, 256, 0, stream>>>(frame, flow, out);
    }
}

// Round 9
// 74.186 us; speedup vs baseline: 1.0969x; 1.0969x over previous
//
#include <hip/hip_runtime.h>

// DenseWarp: out[b,c,y,x] = bilinear(frame[b,c], qy, qx)
//   qy = clip(y - flow[b,0,y,x], 0, H-1), qx = clip(x - flow[b,1,y,x], 0, W-1)
// fp32 in/out. B=4, C=4, H=1080, W=1920.
//
// R9: R5 gather shape restored (1 px per lane-position, adjacent lanes ->
// same gather coalescing, low VGPR) but each thread handles TWO independent
// pixels in separate 64-px chunks (base+t and base+256+t): 2 independent
// load->FMA->store chains per wave for latency hiding, half the waves.
// Two-pass scheme kept: NCHW->NHWC fp16 prepass into d_ws (NT frame reads),
// then gather (2 h8 gathers/px from LLC-resident ws). Bijective XCD swizzle.

#define BB 4
#define CC 4
#define HH 1080
#define WW 1920
#define HW (HH * WW)
#define NPX (BB * HH * WW)              // 8,294,400 pixels (b,y,x)
#define WS_BYTES ((size_t)NPX * CC * 2) // 66,355,200 B
#define NBLK_P (NPX / 4 / 256)          // 8,100  (prepass: 4 px/thread)
#define NBLK_G (NPX / 2 / 256)          // 16,200 (gather: 2 px/thread)
#define NBLK_F (NPX / 256)              // 32,400 (fallback)

typedef _Float16 h8 __attribute__((ext_vector_type(8), aligned(8)));
typedef float f32x4 __attribute__((ext_vector_type(4), aligned(16)));
typedef float f32x2 __attribute__((ext_vector_type(2), aligned(4)));

// m204 bijective XCD swizzle — valid for ANY nblk.
__device__ __forceinline__ int xcd_swizzle(int n, int nblk)
{
    const int q   = nblk >> 3;
    const int r   = nblk & 7;
    const int xcd = n & 7;
    const int loc = n >> 3;
    const int base = (xcd < r) ? xcd * (q + 1) : r * (q + 1) + (xcd - r) * q;
    return base + loc;
}

__global__ __launch_bounds__(256) void nhwc_fp16_prepass(
    const float* __restrict__ frame,
    _Float16* __restrict__ ws)
{
    const int blk = xcd_swizzle(blockIdx.x, NBLK_P);
    const int p   = (blk * 256 + threadIdx.x) * 4;   // first of 4 pixels
    const int x = p % WW;
    const int t = p / WW;
    const int y = t % HH;
    const int b = t / HH;

    const size_t off = (size_t)(b * CC) * HW + (size_t)y * WW + x;
    h8 o1, o2;
#pragma unroll
    for (int c = 0; c < CC; ++c) {
        // nontemporal: frame is read exactly once; keep LLC for ws
        const f32x4 v = __builtin_nontemporal_load(
            reinterpret_cast<const f32x4*>(frame + off + (size_t)c * HW));
        o1[c]     = (_Float16)v.x;
        o1[c + 4] = (_Float16)v.y;
        o2[c]     = (_Float16)v.z;
        o2[c + 4] = (_Float16)v.w;
    }
    // regular stores: ws should be LLC-resident for the gather pass
    *reinterpret_cast<h8*>(ws + (size_t)p * 4)     = o1;
    *reinterpret_cast<h8*>(ws + (size_t)p * 4 + 8) = o2;
}

__global__ __launch_bounds__(256) void dense_warp_gather(
    const _Float16* __restrict__ ws,
    const float* __restrict__ flow,
    float* __restrict__ out)
{
    const int blk  = xcd_swizzle(blockIdx.x, NBLK_G);
    const int base = blk * 512;    // block owns 512 px in two 256-px chunks

    // two independent pixels per thread, each in a lane-adjacent chunk
#pragma unroll
    for (int k = 0; k < 2; ++k) {
        const int p = base + k * 256 + threadIdx.x;
        const int x = p % WW;
        const int t = p / WW;
        const int y = t % HH;
        const int b = t / HH;

        const size_t rowoff = (size_t)y * WW + x;
        const float* __restrict__ flowy = flow + (size_t)(b * 2) * HW;
        const float* __restrict__ flowx = flowy + HW;
        const _Float16* __restrict__ wsb = ws + (size_t)b * HW * 4;
        float* __restrict__ outb = out + (size_t)(b * CC) * HW;

        const float fy = flowy[rowoff];
        const float fx = flowx[rowoff];

        // same op order as reference
        const float qy  = fminf(fmaxf((float)y - fy, 0.0f), (float)(HH - 1));
        const float qx  = fminf(fmaxf((float)x - fx, 0.0f), (float)(WW - 1));
        const float y0f = floorf(qy);
        const float x0f = floorf(qx);
        const float wy  = qy - y0f;
        float       wx  = qx - x0f;
        const int y0 = (int)y0f;
        const int x0 = (int)x0f;
        const int y1 = min(y0 + 1, HH - 1);

        // right-edge: x0==W-1 -> wx==0; load pair at W-2 with wx=1 (identical)
        const bool edge = (x0 > WW - 2);
        const int  xb   = edge ? (WW - 2) : x0;
        if (edge) wx = 1.0f;

        // one 16B load per row covers 4 channels x 2 pixels (NHWC fp16)
        const h8 tp = *reinterpret_cast<const h8*>(wsb + ((size_t)y0 * WW + xb) * 4);
        const h8 bt = *reinterpret_cast<const h8*>(wsb + ((size_t)y1 * WW + xb) * 4);

        const float omwx = 1.0f - wx;
        const float omwy = 1.0f - wy;

#pragma unroll
        for (int c = 0; c < CC; ++c) {
            const float tl = (float)tp[c];
            const float tr = (float)tp[c + 4];
            const float bl = (float)bt[c];
            const float br = (float)bt[c + 4];
            const float top = tl * omwx + tr * wx;
            const float bot = bl * omwx + br * wx;
            const float v   = top * omwy + bot * wy;
            __builtin_nontemporal_store(v, outb + (size_t)c * HW + rowoff);
        }
    }
}

// exact-fp32 single-pass fallback if ws_size is insufficient (R3 kernel)
__global__ __launch_bounds__(256) void dense_warp_fallback(
    const float* __restrict__ frame,
    const float* __restrict__ flow,
    float* __restrict__ out)
{
    const int blk = xcd_swizzle(blockIdx.x, NBLK_F);
    const int p   = blk * 256 + threadIdx.x;
    const int x = p % WW;
    const int t = p / WW;
    const int y = t % HH;
    const int b = t / HH;

    const size_t rowoff = (size_t)y * WW + x;
    const float fy = flow[(size_t)(b * 2 + 0) * HW + rowoff];
    const float fx = flow[(size_t)(b * 2 + 1) * HW + rowoff];

    const float qy  = fminf(fmaxf((float)y - fy, 0.0f), (float)(HH - 1));
    const float qx  = fminf(fmaxf((float)x - fx, 0.0f), (float)(WW - 1));
    const float y0f = floorf(qy);
    const float x0f = floorf(qx);
    const float wy  = qy - y0f;
    float       wx  = qx - x0f;
    const int y0 = (int)y0f;
    const int x0 = (int)x0f;
    const int y1 = min(y0 + 1, HH - 1);
    const bool edge = (x0 > WW - 2);
    const int  xb   = edge ? (WW - 2) : x0;
    if (edge) wx = 1.0f;

    const int i0 = y0 * WW + xb;
    const int i1 = y1 * WW + xb;
    const float omwx = 1.0f - wx;
    const float omwy = 1.0f - wy;

#pragma unroll
    for (int c = 0; c < CC; ++c) {
        const float* fp = frame + (size_t)(b * CC + c) * HW;
        const f32x2 t2 = *reinterpret_cast<const f32x2*>(fp + i0);
        const f32x2 b2 = *reinterpret_cast<const f32x2*>(fp + i1);
        const float top = t2.x * omwx + t2.y * wx;
        const float bot = b2.x * omwx + b2.y * wx;
        const float v   = top * omwy + bot * wy;
        __builtin_nontemporal_store(v, out + (size_t)(b * CC + c) * HW + rowoff);
    }
}

extern "C" void kernel_launch(void* const* d_in, const int* in_sizes, int n_in,
                              void* d_out, int out_size, void* d_ws, size_t ws_size,
                              hipStream_t stream)
{
    const float* frame = (const float*)d_in[0];
    const float* flow  = (const float*)d_in[1];
    float* out = (float*)d_out;

    if (ws_size >= WS_BYTES && d_ws != nullptr) {
        _Float16* ws = (_Float16*)d_ws;
        nhwc_fp16_prepass<<<NBLK_P, 256, 0, stream>>>(frame, ws);
        dense_warp_gather<<<NBLK_G, 256, 0, stream>>>(ws, flow, out);
    } else {
        dense_warp_fallback<<<NBLK_F, 256, 0, stream>>>(frame, flow, out);
    }
}